// Round 3
// baseline (6729.936 us; speedup 1.0000x reference)
//
#include <hip/hip_runtime.h>
#include <math.h>

#define B 512
#define H 256
#define L 256
#define T 64
#define V 128
#define LAYERS 2
#define SOS 0

// ---- workspace layout (in _Float16 elements) ----
// All weights stored f16, k8-blocked: [k8][out][8] -> each lane loads 16B
// (dwordx4), lanes contiguous -> 1KB/wave coalesced.
#define OFF_A 0                      // attn:  [64][256][8]  (K=512 over [e|h])
#define OFF_C 131072                 // comb:  [64][256][8]  (K=512 over [ap|e])
#define OFF_G 262144                 // gru:   [2 layers][6 mats][32][256][8]
#define GRU_LAYER_STRIDE (6 * 65536) // 393216
#define GRU_MAT_STRIDE 65536
#define OFF_O (OFF_G + LAYERS * GRU_LAYER_STRIDE) // out: [32][128][8]
#define WS_HALVES (OFF_O + 32768)    // 1,081,344 halves = 2.16 MB

typedef _Float16 half8 __attribute__((ext_vector_type(8)));
typedef _Float16 half2t __attribute__((ext_vector_type(2)));
typedef float f4v __attribute__((ext_vector_type(4)));

#if __has_builtin(__builtin_nontemporal_load)
#define NT_LOAD(p) __builtin_nontemporal_load(p)
#else
#define NT_LOAD(p) (*(p))
#endif

__device__ __forceinline__ float fdot2(half2t a, half2t b, float c) {
#if __has_builtin(__builtin_amdgcn_fdot2)
    return __builtin_amdgcn_fdot2(a, b, c, false);
#else
    return c + (float)a[0] * (float)b[0] + (float)a[1] * (float)b[1];
#endif
}

union H8 {
    half8 v;
    half2t p[4];
};

__device__ __forceinline__ float sigmoidf_(float v) {
    return 1.f / (1.f + __expf(-v));
}
__device__ __forceinline__ float fast_tanh(float v) {
    v = fminf(fmaxf(v, -15.f), 15.f);
    float e = __expf(-2.f * v);
    return (1.f - e) / (1.f + e);
}

// One-time repack of all weights to f16 k8-blocked layouts in ws.
__global__ void prep_pack(const float* __restrict__ attn_w,
                          const float* __restrict__ comb_w,
                          const float* __restrict__ gru_w_ih,
                          const float* __restrict__ gru_w_hh,
                          const float* __restrict__ out_w,
                          _Float16* __restrict__ ws) {
    int stride = gridDim.x * blockDim.x;
    for (int idx = blockIdx.x * blockDim.x + threadIdx.x; idx < WS_HALVES; idx += stride) {
        float val;
        if (idx < OFF_C) {
            int i = idx & 7, r = idx >> 3;
            int l = r & 255, k8 = r >> 8;
            val = attn_w[l * 512 + k8 * 8 + i];
        } else if (idx < OFF_G) {
            int e = idx - OFF_C;
            int i = e & 7, r = e >> 3;
            int hh = r & 255, k8 = r >> 8;
            val = comb_w[hh * 512 + k8 * 8 + i];
        } else if (idx < OFF_O) {
            int e = idx - OFF_G;
            int layer = e / GRU_LAYER_STRIDE;
            e -= layer * GRU_LAYER_STRIDE;
            int mat = e >> 16;
            e &= 65535;
            int i = e & 7, r = e >> 3;
            int j = r & 255, k8 = r >> 8;
            int k = k8 * 8 + i;
            const float* src = (mat < 3) ? gru_w_ih : gru_w_hh;
            int gate = (mat < 3) ? mat : mat - 3;
            val = src[layer * (768 * 256) + (gate * 256 + j) * 256 + k];
        } else {
            int e = idx - OFF_O;
            int i = e & 7, r = e >> 3;
            int v = r & 127, k8 = r >> 7;
            val = out_w[v * 256 + k8 * 8 + i];
        }
        ws[idx] = (_Float16)val;
    }
}

// 256 blocks x 1024 threads (16 waves, 1 block/CU -> 4 waves/SIMD).
// Block owns 2 batch rows; group g = tid>>9 owns row b0+g with 512 threads.
// Within a group, thread = (h = s&255, p = s>>8): p splits the reduction
// (attn/comb K-halves; GRU ih vs hh gate triples; logits 4-way K-split).
// Biases are folded into partials so reduce stages are pure adds.
__global__ __launch_bounds__(1024) void decoder_kernel(
    const float* __restrict__ x,        // [B][H][1][L] fp32
    const int* __restrict__ y,          // [B][T]
    const float* __restrict__ emb,      // [V][H]
    const float* __restrict__ attn_b,   // [L]
    const float* __restrict__ comb_b,   // [H]
    const float* __restrict__ gru_b_ih, // [2][3H]
    const float* __restrict__ gru_b_hh, // [2][3H]
    const float* __restrict__ out_b,    // [V]
    const _Float16* __restrict__ wsh,
    float* __restrict__ out) {
    __shared__ __align__(16) _Float16 ehf[2][512];         // [e | h0] f16
    __shared__ __align__(16) _Float16 hfs[LAYERS][2][256]; // h f16 (dot input)
    __shared__ __align__(16) float h32[LAYERS][2][256];    // h fp32 (blend)
    __shared__ __align__(16) _Float16 apf[2][256];         // applied f16
    __shared__ __align__(16) _Float16 gf[2][256];          // comb output f16
    __shared__ __align__(16) float aw32[2][256];           // attn weights fp32
    __shared__ __align__(16) float part32[2][6][256];      // stage partials

    const int tid = threadIdx.x;
    const int g = tid >> 9;       // row group 0/1
    const int s = tid & 511;      // thread-in-group
    const int h = s & 255;        // output-unit index
    const int p = s >> 8;         // split part 0/1
    const int lane = tid & 63;
    const int b = blockIdx.x * 2 + g;

    const _Float16* AW = wsh + OFF_A;
    const _Float16* CW = wsh + OFF_C;
    const _Float16* OW = wsh + OFF_O;

    // ---- per-role bias preloads ----
    const float ab = (p == 0) ? attn_b[h] : 0.f;   // attn bias, p0 partial
    const float cb = (p == 0) ? comb_b[h] : 0.f;   // comb bias, p0 partial
    const float ob = (s < V) ? out_b[s] : 0.f;     // out bias, q==0 partial
    // GRU: p=0 uses b_ih triple, p=1 uses b_hh triple (folded into partials)
    float gbR[LAYERS], gbZ[LAYERS], gbN[LAYERS];
#pragma unroll
    for (int l = 0; l < LAYERS; ++l) {
        const float* gb = ((p == 0) ? gru_b_ih : gru_b_hh) + l * 768;
        gbR[l] = gb[h];
        gbZ[l] = gb[256 + h];
        gbN[l] = gb[512 + h];
    }

    // ---- init state ----
    if (p == 0) {
#pragma unroll
        for (int l = 0; l < LAYERS; ++l) {
            h32[l][g][h] = 0.f;
            hfs[l][g][h] = (_Float16)0.f;
        }
        ehf[g][256 + h] = (_Float16)0.f;
    }
    __syncthreads();

    for (int t = 0; t < T; ++t) {
        // ---- 1: embedding gather ----
        if (p == 0) {
            int tok = (t == 0) ? SOS : y[b * T + (t - 1)];
            ehf[g][h] = (_Float16)emb[tok * H + h];
        }
        __syncthreads();

        // ---- 2: attn score partial: thread (l=h, p); K-half p over [e|h0] ----
        {
            float a0 = 0.f, a1 = 0.f, a2 = 0.f, a3 = 0.f;
            const _Float16* ap = &ehf[g][p << 8];
            const _Float16* wp = AW + (((p << 5) << 8) + h) * 8;
#pragma unroll 4
            for (int k8 = 0; k8 < 32; ++k8) {
                H8 uw, ua;
                uw.v = *(const half8*)(wp + (k8 << 11));
                ua.v = *(const half8*)(ap + (k8 << 3));
                a0 = fdot2(uw.p[0], ua.p[0], a0);
                a1 = fdot2(uw.p[1], ua.p[1], a1);
                a2 = fdot2(uw.p[2], ua.p[2], a2);
                a3 = fdot2(uw.p[3], ua.p[3], a3);
            }
            part32[g][p][h] = a0 + a1 + a2 + a3 + ab;
        }
        __syncthreads();

        // ---- 3: softmax over L (wave 0 of each group) + attns output ----
        if (s < 64) {
            float s0 = part32[g][0][lane] + part32[g][1][lane];
            float s1 = part32[g][0][lane + 64] + part32[g][1][lane + 64];
            float s2 = part32[g][0][lane + 128] + part32[g][1][lane + 128];
            float s3 = part32[g][0][lane + 192] + part32[g][1][lane + 192];
            float m = fmaxf(fmaxf(s0, s1), fmaxf(s2, s3));
            for (int off = 32; off; off >>= 1) m = fmaxf(m, __shfl_xor(m, off));
            float e0 = __expf(s0 - m), e1 = __expf(s1 - m);
            float e2 = __expf(s2 - m), e3 = __expf(s3 - m);
            float sm = e0 + e1 + e2 + e3;
            for (int off = 32; off; off >>= 1) sm += __shfl_xor(sm, off);
            float inv = 1.f / sm;
            e0 *= inv; e1 *= inv; e2 *= inv; e3 *= inv;
            aw32[g][lane] = e0;
            aw32[g][lane + 64] = e1;
            aw32[g][lane + 128] = e2;
            aw32[g][lane + 192] = e3;
            size_t base = (size_t)B * V * T + ((size_t)b * T + t) * L;
            out[base + lane] = e0;
            out[base + lane + 64] = e1;
            out[base + lane + 128] = e2;
            out[base + lane + 192] = e3;
        }
        __syncthreads();

        // ---- 4: applied partial: thread (h, p) over l-half p ----
        {
            const float* xrow = x + ((size_t)b * H + h) * L + (p << 7);
            const float* wr = &aw32[g][p << 7];
            float a0 = 0.f, a1 = 0.f;
#pragma unroll 4
            for (int l = 0; l < 128; l += 8) {
                f4v x0 = NT_LOAD((const f4v*)(xrow + l));
                f4v x1 = NT_LOAD((const f4v*)(xrow + l + 4));
                float4 w0 = *(const float4*)(wr + l);
                float4 w1 = *(const float4*)(wr + l + 4);
                a0 += x0.x * w0.x + x0.y * w0.y + x0.z * w0.z + x0.w * w0.w;
                a1 += x1.x * w1.x + x1.y * w1.y + x1.z * w1.z + x1.w * w1.w;
            }
            part32[g][p][h] = a0 + a1;
        }
        __syncthreads();

        // ---- 5: applied reduce -> f16 ----
        if (p == 0) apf[g][h] = (_Float16)(part32[g][0][h] + part32[g][1][h]);
        __syncthreads();

        // ---- 6: comb partial: p0 = applied-half, p1 = e-half ----
        {
            float a0 = 0.f, a1 = 0.f, a2 = 0.f, a3 = 0.f;
            const _Float16* ap = (p == 0) ? &apf[g][0] : &ehf[g][0];
            const _Float16* wp = CW + (((p << 5) << 8) + h) * 8;
#pragma unroll 4
            for (int k8 = 0; k8 < 32; ++k8) {
                H8 uw, ua;
                uw.v = *(const half8*)(wp + (k8 << 11));
                ua.v = *(const half8*)(ap + (k8 << 3));
                a0 = fdot2(uw.p[0], ua.p[0], a0);
                a1 = fdot2(uw.p[1], ua.p[1], a1);
                a2 = fdot2(uw.p[2], ua.p[2], a2);
                a3 = fdot2(uw.p[3], ua.p[3], a3);
            }
            part32[g][p][h] = a0 + a1 + a2 + a3 + cb;
        }
        __syncthreads();

        // ---- 7: comb reduce + relu -> f16 ----
        if (p == 0)
            gf[g][h] = (_Float16)fmaxf(part32[g][0][h] + part32[g][1][h], 0.f);
        __syncthreads();

        // ---- 8..11: 2-layer GRU ----
#pragma unroll
        for (int layer = 0; layer < LAYERS; ++layer) {
            // dots: p=0 -> input triple (r,z,n) on xin; p=1 -> hidden triple on h
            {
                const _Float16* GW = wsh + OFF_G + layer * GRU_LAYER_STRIDE +
                                     (3 * p) * GRU_MAT_STRIDE;
                const _Float16* act =
                    (p == 1) ? &hfs[layer][g][0]
                             : ((layer == 0) ? &gf[g][0] : &hfs[0][g][0]);
                float aR = 0.f, aZ = 0.f, aN = 0.f;
                const _Float16* w0p = GW + h * 8;
#pragma unroll 4
                for (int k8 = 0; k8 < 32; ++k8) {
                    H8 xa, w0, w1, w2;
                    xa.v = *(const half8*)(act + (k8 << 3));
                    const int off = k8 << 11;
                    w0.v = *(const half8*)(w0p + off);
                    w1.v = *(const half8*)(w0p + GRU_MAT_STRIDE + off);
                    w2.v = *(const half8*)(w0p + 2 * GRU_MAT_STRIDE + off);
#pragma unroll
                    for (int q = 0; q < 4; ++q) {
                        aR = fdot2(w0.p[q], xa.p[q], aR);
                        aZ = fdot2(w1.p[q], xa.p[q], aZ);
                        aN = fdot2(w2.p[q], xa.p[q], aN);
                    }
                }
                part32[g][3 * p + 0][h] = aR + gbR[layer];
                part32[g][3 * p + 1][h] = aZ + gbZ[layer];
                part32[g][3 * p + 2][h] = aN + gbN[layer];
            }
            __syncthreads();
            // combine (p==0): gate math + state update
            if (p == 0) {
                float rr = sigmoidf_(part32[g][0][h] + part32[g][3][h]);
                float zz = sigmoidf_(part32[g][1][h] + part32[g][4][h]);
                float nn = fast_tanh(part32[g][2][h] + rr * part32[g][5][h]);
                float hnew = (1.f - zz) * nn + zz * h32[layer][g][h];
                h32[layer][g][h] = hnew;
                hfs[layer][g][h] = (_Float16)hnew;
                if (layer == 0) ehf[g][256 + h] = (_Float16)hnew;
            }
            __syncthreads();
        }

        // ---- 12: logits partial: thread (v = s&127, q = s>>7), K-chunk q ----
        {
            const int v = s & 127, q = s >> 7;
            float a0 = 0.f, a1 = 0.f, a2 = 0.f, a3 = 0.f;
            const _Float16* hp = &hfs[1][g][q << 6];
            const _Float16* wp = OW + (((q << 3) << 7) + v) * 8;
#pragma unroll
            for (int k8 = 0; k8 < 8; ++k8) {
                H8 uw, ua;
                uw.v = *(const half8*)(wp + (k8 << 10));
                ua.v = *(const half8*)(hp + (k8 << 3));
                a0 = fdot2(uw.p[0], ua.p[0], a0);
                a1 = fdot2(uw.p[1], ua.p[1], a1);
                a2 = fdot2(uw.p[2], ua.p[2], a2);
                a3 = fdot2(uw.p[3], ua.p[3], a3);
            }
            part32[g][q][v] = a0 + a1 + a2 + a3 + ((q == 0) ? ob : 0.f);
        }
        __syncthreads();

        // ---- 13: log_softmax over V (wave 0 of each group) + outs ----
        if (s < 64) {
            float l0 = part32[g][0][lane] + part32[g][1][lane] +
                       part32[g][2][lane] + part32[g][3][lane];
            float l1 = part32[g][0][lane + 64] + part32[g][1][lane + 64] +
                       part32[g][2][lane + 64] + part32[g][3][lane + 64];
            float m = fmaxf(l0, l1);
            for (int off = 32; off; off >>= 1) m = fmaxf(m, __shfl_xor(m, off));
            float sm = __expf(l0 - m) + __expf(l1 - m);
            for (int off = 32; off; off >>= 1) sm += __shfl_xor(sm, off);
            float lse = m + __logf(sm);
            size_t base = (size_t)b * V * T + (size_t)t;
            out[base + (size_t)lane * T] = l0 - lse;
            out[base + (size_t)(lane + 64) * T] = l1 - lse;
        }
        __syncthreads();
    }
}

extern "C" void kernel_launch(void* const* d_in, const int* in_sizes, int n_in,
                              void* d_out, int out_size, void* d_ws, size_t ws_size,
                              hipStream_t stream) {
    const float* x = (const float*)d_in[0];
    const int* y = (const int*)d_in[1];
    const float* emb = (const float*)d_in[2];
    const float* attn_w = (const float*)d_in[3];
    const float* attn_b = (const float*)d_in[4];
    const float* comb_w = (const float*)d_in[5];
    const float* comb_b = (const float*)d_in[6];
    const float* gru_w_ih = (const float*)d_in[7];
    const float* gru_w_hh = (const float*)d_in[8];
    const float* gru_b_ih = (const float*)d_in[9];
    const float* gru_b_hh = (const float*)d_in[10];
    const float* out_w = (const float*)d_in[11];
    const float* out_b = (const float*)d_in[12];
    float* out = (float*)d_out;
    _Float16* ws = (_Float16*)d_ws;

    prep_pack<<<512, 256, 0, stream>>>(attn_w, comb_w, gru_w_ih, gru_w_hh, out_w, ws);
    decoder_kernel<<<B / 2, 1024, 0, stream>>>(x, y, emb, attn_b, comb_b, gru_b_ih,
                                               gru_b_hh, out_b, ws, out);
}

// Round 4
// 3660.774 us; speedup vs baseline: 1.8384x; 1.8384x over previous
//
#include <hip/hip_runtime.h>
#include <math.h>

#define B 512
#define H 256
#define L 256
#define T 64
#define V 128
#define LAYERS 2
#define SOS 0

// ---- workspace layout (in _Float16 elements) ----
// All weights stored f16, k8-blocked: [k8][out][8] -> each lane loads 16B
// (dwordx4), lanes contiguous -> 1KB/wave coalesced.
#define OFF_A 0                      // attn:  [64][256][8]  (K=512 over [e|h])
#define OFF_C 131072                 // comb:  [64][256][8]  (K=512 over [ap|e])
#define OFF_G 262144                 // gru:   [2 layers][6 mats][32][256][8]
#define GRU_LAYER_STRIDE (6 * 65536) // 393216
#define GRU_MAT_STRIDE 65536
#define OFF_O (OFF_G + LAYERS * GRU_LAYER_STRIDE) // out: [32][128][8]
#define WS_HALVES (OFF_O + 32768)    // 1,081,344 halves = 2.16 MB
// xT: [b][l8][h][8] f16 — the einsum operand, coalesced + L3-resident (67 MB)
#define OFF_XT WS_HALVES
#define XT_B_STRIDE (32 * 256 * 8)   // 65536 halves per batch row
#define XT_HALVES ((size_t)B * XT_B_STRIDE)
#define WS_NEED_BYTES ((size_t)(OFF_XT + XT_HALVES) * 2)

typedef _Float16 half8 __attribute__((ext_vector_type(8)));
typedef _Float16 half2t __attribute__((ext_vector_type(2)));

__device__ __forceinline__ float fdot2(half2t a, half2t b, float c) {
#if __has_builtin(__builtin_amdgcn_fdot2)
    return __builtin_amdgcn_fdot2(a, b, c, false);
#else
    return c + (float)a[0] * (float)b[0] + (float)a[1] * (float)b[1];
#endif
}

union H8 {
    half8 v;
    half2t p[4];
};

__device__ __forceinline__ float sigmoidf_(float v) {
    return 1.f / (1.f + __expf(-v));
}
__device__ __forceinline__ float fast_tanh(float v) {
    v = fminf(fmaxf(v, -15.f), 15.f);
    float e = __expf(-2.f * v);
    return (1.f - e) / (1.f + e);
}

// One-time repack of all weights to f16 k8-blocked layouts in ws.
__global__ void prep_pack(const float* __restrict__ attn_w,
                          const float* __restrict__ comb_w,
                          const float* __restrict__ gru_w_ih,
                          const float* __restrict__ gru_w_hh,
                          const float* __restrict__ out_w,
                          _Float16* __restrict__ ws) {
    int stride = gridDim.x * blockDim.x;
    for (int idx = blockIdx.x * blockDim.x + threadIdx.x; idx < WS_HALVES; idx += stride) {
        float val;
        if (idx < OFF_C) {
            int i = idx & 7, r = idx >> 3;
            int l = r & 255, k8 = r >> 8;
            val = attn_w[l * 512 + k8 * 8 + i];
        } else if (idx < OFF_G) {
            int e = idx - OFF_C;
            int i = e & 7, r = e >> 3;
            int hh = r & 255, k8 = r >> 8;
            val = comb_w[hh * 512 + k8 * 8 + i];
        } else if (idx < OFF_O) {
            int e = idx - OFF_G;
            int layer = e / GRU_LAYER_STRIDE;
            e -= layer * GRU_LAYER_STRIDE;
            int mat = e >> 16;
            e &= 65535;
            int i = e & 7, r = e >> 3;
            int j = r & 255, k8 = r >> 8;
            int k = k8 * 8 + i;
            const float* src = (mat < 3) ? gru_w_ih : gru_w_hh;
            int gate = (mat < 3) ? mat : mat - 3;
            val = src[layer * (768 * 256) + (gate * 256 + j) * 256 + k];
        } else {
            int e = idx - OFF_O;
            int i = e & 7, r = e >> 3;
            int v = r & 127, k8 = r >> 7;
            val = out_w[v * 256 + k8 * 8 + i];
        }
        ws[idx] = (_Float16)val;
    }
}

// x[b][h][l] fp32 -> xT[b][l8][h][8] f16 (k8-blocked over l, lane-coalesced
// writes: consecutive h -> consecutive 16B).
__global__ void prep_x(const float* __restrict__ x, _Float16* __restrict__ xt) {
    const int b = blockIdx.x;
    const int h = threadIdx.x;
    const float* xr = x + ((size_t)b * H + h) * L;
    _Float16* base = xt + (size_t)b * XT_B_STRIDE + h * 8;
#pragma unroll 4
    for (int k8 = 0; k8 < 32; ++k8) {
        float4 v0 = *(const float4*)(xr + k8 * 8);
        float4 v1 = *(const float4*)(xr + k8 * 8 + 4);
        half8 o;
        o[0] = (_Float16)v0.x; o[1] = (_Float16)v0.y;
        o[2] = (_Float16)v0.z; o[3] = (_Float16)v0.w;
        o[4] = (_Float16)v1.x; o[5] = (_Float16)v1.y;
        o[6] = (_Float16)v1.z; o[7] = (_Float16)v1.w;
        *(half8*)(base + k8 * 2048) = o;
    }
}

// 256 blocks x 512 threads. Block owns 2 batch rows; group g = tid>>8 owns
// row b0+g with its 256 threads (4 waves). All LDS activation reads are
// wave-broadcasts (same address) -> conflict-free. Weights (and xT when
// USE_XT) stream from L2/L3 as f16 dwordx4, consumed by v_dot2_f32_f16.
template <bool USE_XT>
__global__ __launch_bounds__(512, 2) void decoder_kernel(
    const float* __restrict__ x,        // [B][H][1][L] fp32
    const int* __restrict__ y,          // [B][T]
    const float* __restrict__ emb,      // [V][H]
    const float* __restrict__ attn_b,   // [L]
    const float* __restrict__ comb_b,   // [H]
    const float* __restrict__ gru_b_ih, // [2][3H]
    const float* __restrict__ gru_b_hh, // [2][3H]
    const float* __restrict__ out_b,    // [V]
    const _Float16* __restrict__ wsh,
    const _Float16* __restrict__ xt,    // [B][32][256][8] f16 (if USE_XT)
    float* __restrict__ out) {
    __shared__ __align__(16) _Float16 ehf[2][512];         // [e | h0] f16
    __shared__ __align__(16) _Float16 hfs[LAYERS][2][256]; // h f16 (dot input)
    __shared__ __align__(16) float h32[LAYERS][2][256];    // h fp32 (blend)
    __shared__ __align__(16) _Float16 apf[2][256];         // applied f16
    __shared__ __align__(16) _Float16 gf[2][256];          // comb output f16
    __shared__ __align__(16) _Float16 awf[2][256];         // attn weights f16
    __shared__ __align__(16) float aw32[2][256];           // attn weights fp32
    __shared__ __align__(16) float sc[2][256];             // raw scores
    __shared__ __align__(16) float lg[2][128];             // logits

    const int tid = threadIdx.x;
    const int g = tid >> 8;      // row group 0/1
    const int h = tid & 255;     // output-unit index within group
    const int lane = tid & 63;
    const int wgrp = (tid >> 6) & 3; // wave index within group
    const int b = blockIdx.x * 2 + g;

    const _Float16* AW = wsh + OFF_A;
    const _Float16* CW = wsh + OFF_C;
    const _Float16* OW = wsh + OFF_O;

    // ---- preload biases into registers (constant thread role) ----
    const float ab = attn_b[h];
    const float cb = comb_b[h];
    const float ob = (h < V) ? out_b[h] : 0.f;
    float b_ir[LAYERS], b_iz[LAYERS], b_in[LAYERS], b_hr[LAYERS], b_hz[LAYERS], b_hn[LAYERS];
#pragma unroll
    for (int l = 0; l < LAYERS; ++l) {
        b_ir[l] = gru_b_ih[l * 768 + h];
        b_iz[l] = gru_b_ih[l * 768 + 256 + h];
        b_in[l] = gru_b_ih[l * 768 + 512 + h];
        b_hr[l] = gru_b_hh[l * 768 + h];
        b_hz[l] = gru_b_hh[l * 768 + 256 + h];
        b_hn[l] = gru_b_hh[l * 768 + 512 + h];
    }

    // ---- init state ----
#pragma unroll
    for (int l = 0; l < LAYERS; ++l) {
        h32[l][g][h] = 0.f;
        hfs[l][g][h] = (_Float16)0.f;
    }
    ehf[g][256 + h] = (_Float16)0.f;
    __syncthreads();

    for (int t = 0; t < T; ++t) {
        // ---- embedding gather (tok uniform per group -> scalar load) ----
        int tok = (t == 0) ? SOS : y[b * T + (t - 1)];
        ehf[g][h] = (_Float16)emb[tok * H + h];
        __syncthreads();

        // ---- attn scores: thread = output l; K=512 over [e|h0] ----
        {
            float a0 = 0.f, a1 = 0.f, a2 = 0.f, a3 = 0.f;
            const _Float16* ap = &ehf[g][0];
#pragma unroll 4
            for (int k8 = 0; k8 < 64; ++k8) {
                H8 uw, ua;
                uw.v = *(const half8*)(AW + (((k8 << 8) + h) << 3));
                ua.v = *(const half8*)(ap + (k8 << 3));
                a0 = fdot2(uw.p[0], ua.p[0], a0);
                a1 = fdot2(uw.p[1], ua.p[1], a1);
                a2 = fdot2(uw.p[2], ua.p[2], a2);
                a3 = fdot2(uw.p[3], ua.p[3], a3);
            }
            sc[g][h] = a0 + a1 + a2 + a3 + ab;
        }
        __syncthreads();

        // ---- softmax over L (wave 0 of each group) + attns output ----
        if (wgrp == 0) {
            float s0 = sc[g][lane], s1 = sc[g][lane + 64];
            float s2 = sc[g][lane + 128], s3 = sc[g][lane + 192];
            float m = fmaxf(fmaxf(s0, s1), fmaxf(s2, s3));
            for (int off = 32; off; off >>= 1) m = fmaxf(m, __shfl_xor(m, off));
            float e0 = __expf(s0 - m), e1 = __expf(s1 - m);
            float e2 = __expf(s2 - m), e3 = __expf(s3 - m);
            float s = e0 + e1 + e2 + e3;
            for (int off = 32; off; off >>= 1) s += __shfl_xor(s, off);
            float inv = 1.f / s;
            e0 *= inv; e1 *= inv; e2 *= inv; e3 *= inv;
            if (USE_XT) {
                awf[g][lane] = (_Float16)e0;
                awf[g][lane + 64] = (_Float16)e1;
                awf[g][lane + 128] = (_Float16)e2;
                awf[g][lane + 192] = (_Float16)e3;
            } else {
                aw32[g][lane] = e0;
                aw32[g][lane + 64] = e1;
                aw32[g][lane + 128] = e2;
                aw32[g][lane + 192] = e3;
            }
            size_t base = (size_t)B * V * T + ((size_t)b * T + t) * L;
            out[base + lane] = e0;
            out[base + lane + 64] = e1;
            out[base + lane + 128] = e2;
            out[base + lane + 192] = e3;
        }
        __syncthreads();

        // ---- applied[h] = sum_l aw[l] * x[b][:,l,h] ----
        if (USE_XT) {
            // coalesced f16 k8-blocked xT, same shape as the weight loops
            const _Float16* xrow = xt + (size_t)b * XT_B_STRIDE + (h << 3);
            const _Float16* ap = &awf[g][0];
            float a0 = 0.f, a1 = 0.f, a2 = 0.f, a3 = 0.f;
#pragma unroll 4
            for (int k8 = 0; k8 < 32; ++k8) {
                H8 uw, ua;
                uw.v = *(const half8*)(xrow + (k8 << 11));
                ua.v = *(const half8*)(ap + (k8 << 3));
                a0 = fdot2(uw.p[0], ua.p[0], a0);
                a1 = fdot2(uw.p[1], ua.p[1], a1);
                a2 = fdot2(uw.p[2], ua.p[2], a2);
                a3 = fdot2(uw.p[3], ua.p[3], a3);
            }
            apf[g][h] = (_Float16)(a0 + a1 + a2 + a3);
        } else {
            const float* xrow = x + ((size_t)b * H + h) * L;
            float a0 = 0.f, a1 = 0.f;
#pragma unroll 4
            for (int l = 0; l < L; l += 8) {
                float4 x0 = *(const float4*)(xrow + l);
                float4 x1 = *(const float4*)(xrow + l + 4);
                float4 w0 = *(const float4*)&aw32[g][l];
                float4 w1 = *(const float4*)&aw32[g][l + 4];
                a0 += x0.x * w0.x + x0.y * w0.y + x0.z * w0.z + x0.w * w0.w;
                a1 += x1.x * w1.x + x1.y * w1.y + x1.z * w1.z + x1.w * w1.w;
            }
            apf[g][h] = (_Float16)(a0 + a1);
        }
        __syncthreads();

        // ---- comb: thread = output h; K=512 over [applied | e] ----
        {
            float a0 = 0.f, a1 = 0.f, a2 = 0.f, a3 = 0.f;
#pragma unroll 4
            for (int k8 = 0; k8 < 32; ++k8) {
                H8 uw, ua;
                uw.v = *(const half8*)(CW + (((k8 << 8) + h) << 3));
                ua.v = *(const half8*)(&apf[g][0] + (k8 << 3));
                a0 = fdot2(uw.p[0], ua.p[0], a0);
                a1 = fdot2(uw.p[1], ua.p[1], a1);
                a2 = fdot2(uw.p[2], ua.p[2], a2);
                a3 = fdot2(uw.p[3], ua.p[3], a3);
            }
#pragma unroll 4
            for (int k8 = 32; k8 < 64; ++k8) {
                H8 uw, ua;
                uw.v = *(const half8*)(CW + (((k8 << 8) + h) << 3));
                ua.v = *(const half8*)(&ehf[g][0] + ((k8 - 32) << 3));
                a0 = fdot2(uw.p[0], ua.p[0], a0);
                a1 = fdot2(uw.p[1], ua.p[1], a1);
                a2 = fdot2(uw.p[2], ua.p[2], a2);
                a3 = fdot2(uw.p[3], ua.p[3], a3);
            }
            gf[g][h] = (_Float16)fmaxf(a0 + a1 + a2 + a3 + cb, 0.f);
        }
        __syncthreads();

        // ---- 2-layer GRU: thread = hidden unit h; 6 dot2 accumulators ----
#pragma unroll
        for (int layer = 0; layer < LAYERS; ++layer) {
            const _Float16* GW = wsh + OFF_G + layer * GRU_LAYER_STRIDE;
            const _Float16* xinp = (layer == 0) ? &gf[g][0] : &hfs[0][g][0];
            const _Float16* hinp = &hfs[layer][g][0];
            float aR = 0.f, aZ = 0.f, aN = 0.f, aRh = 0.f, aZh = 0.f, aNh = 0.f;
#pragma unroll 4
            for (int k8 = 0; k8 < 32; ++k8) {
                H8 xa, ha, w0, w1, w2, w3, w4, w5;
                xa.v = *(const half8*)(xinp + (k8 << 3));
                ha.v = *(const half8*)(hinp + (k8 << 3));
                const int off = ((k8 << 8) + h) << 3;
                w0.v = *(const half8*)(GW + 0 * GRU_MAT_STRIDE + off);
                w1.v = *(const half8*)(GW + 1 * GRU_MAT_STRIDE + off);
                w2.v = *(const half8*)(GW + 2 * GRU_MAT_STRIDE + off);
                w3.v = *(const half8*)(GW + 3 * GRU_MAT_STRIDE + off);
                w4.v = *(const half8*)(GW + 4 * GRU_MAT_STRIDE + off);
                w5.v = *(const half8*)(GW + 5 * GRU_MAT_STRIDE + off);
#pragma unroll
                for (int p = 0; p < 4; ++p) {
                    aR = fdot2(w0.p[p], xa.p[p], aR);
                    aZ = fdot2(w1.p[p], xa.p[p], aZ);
                    aN = fdot2(w2.p[p], xa.p[p], aN);
                    aRh = fdot2(w3.p[p], ha.p[p], aRh);
                    aZh = fdot2(w4.p[p], ha.p[p], aZh);
                    aNh = fdot2(w5.p[p], ha.p[p], aNh);
                }
            }
            float rr = sigmoidf_(aR + b_ir[layer] + aRh + b_hr[layer]);
            float zz = sigmoidf_(aZ + b_iz[layer] + aZh + b_hz[layer]);
            float nn = fast_tanh(aN + b_in[layer] + rr * (aNh + b_hn[layer]));
            float hnew = (1.f - zz) * nn + zz * h32[layer][g][h];
            __syncthreads();  // all dot reads of old h / xin complete
            h32[layer][g][h] = hnew;
            hfs[layer][g][h] = (_Float16)hnew;
            if (layer == 0) ehf[g][256 + h] = (_Float16)hnew;
            __syncthreads();
        }

        // ---- logits: threads h<128 ----
        if (h < V) {
            float a0 = 0.f, a1 = 0.f, a2 = 0.f, a3 = 0.f;
            const _Float16* hp = &hfs[1][g][0];
#pragma unroll 4
            for (int k8 = 0; k8 < 32; ++k8) {
                H8 uw, ua;
                uw.v = *(const half8*)(OW + (((k8 << 7) + h) << 3));
                ua.v = *(const half8*)(hp + (k8 << 3));
                a0 = fdot2(uw.p[0], ua.p[0], a0);
                a1 = fdot2(uw.p[1], ua.p[1], a1);
                a2 = fdot2(uw.p[2], ua.p[2], a2);
                a3 = fdot2(uw.p[3], ua.p[3], a3);
            }
            lg[g][h] = a0 + a1 + a2 + a3 + ob;
        }
        __syncthreads();

        // ---- log_softmax over V (wave 0 of each group) + outs output ----
        if (wgrp == 0) {
            float l0 = lg[g][lane], l1 = lg[g][lane + 64];
            float m = fmaxf(l0, l1);
            for (int off = 32; off; off >>= 1) m = fmaxf(m, __shfl_xor(m, off));
            float s = __expf(l0 - m) + __expf(l1 - m);
            for (int off = 32; off; off >>= 1) s += __shfl_xor(s, off);
            float lse = m + __logf(s);
            size_t base = (size_t)b * V * T + (size_t)t;
            out[base + (size_t)lane * T] = l0 - lse;
            out[base + (size_t)(lane + 64) * T] = l1 - lse;
        }
        __syncthreads();
    }
}

extern "C" void kernel_launch(void* const* d_in, const int* in_sizes, int n_in,
                              void* d_out, int out_size, void* d_ws, size_t ws_size,
                              hipStream_t stream) {
    const float* x = (const float*)d_in[0];
    const int* y = (const int*)d_in[1];
    const float* emb = (const float*)d_in[2];
    const float* attn_w = (const float*)d_in[3];
    const float* attn_b = (const float*)d_in[4];
    const float* comb_w = (const float*)d_in[5];
    const float* comb_b = (const float*)d_in[6];
    const float* gru_w_ih = (const float*)d_in[7];
    const float* gru_w_hh = (const float*)d_in[8];
    const float* gru_b_ih = (const float*)d_in[9];
    const float* gru_b_hh = (const float*)d_in[10];
    const float* out_w = (const float*)d_in[11];
    const float* out_b = (const float*)d_in[12];
    float* out = (float*)d_out;
    _Float16* ws = (_Float16*)d_ws;

    prep_pack<<<512, 256, 0, stream>>>(attn_w, comb_w, gru_w_ih, gru_w_hh, out_w, ws);
    if (ws_size >= WS_NEED_BYTES) {
        _Float16* xt = ws + OFF_XT;
        prep_x<<<B, 256, 0, stream>>>(x, xt);
        decoder_kernel<true><<<B / 2, 512, 0, stream>>>(
            x, y, emb, attn_b, comb_b, gru_b_ih, gru_b_hh, out_b, ws, xt, out);
    } else {
        decoder_kernel<false><<<B / 2, 512, 0, stream>>>(
            x, y, emb, attn_b, comb_b, gru_b_ih, gru_b_hh, out_b, ws, nullptr, out);
    }
}